// Round 5
// baseline (567.446 us; speedup 1.0000x reference)
//
#include <hip/hip_runtime.h>

// ConvCaps EM routing, MI355X — multi-dispatch, occupancy-tuned.
// Geometry: b=16 -> 576 positions; N=288 input caps; C=32; ITERS=3.
//
// R1  fused 4-wave:  107us (VALUBusy 40%, Occ 20%)
// R4  4-chunk split: 123us; E-pass 53.7us, VALUBusy 45%, Occ 31%.
//     LDS 27.1KB/block -> only 6 blocks/CU; 17.4KB of it was reduce scratch.
// R5: two-phase half-split reduction -> LDS ~18.4KB -> 8 blocks/CU (32-wave cap),
//     __launch_bounds__(256,8) pins VGPR<=64 (natural 60), pointer-increment
//     addressing in the n-loop. Deterministic (no atomics).

#define LN2PI 1.8378770664093453f

// ---------------- M-pass kernel ----------------
// grid (576, NCH), block 256 (4 waves). pos=blockIdx.x, chunk=blockIdx.y.
// Each half-wave owns one n per step; lane&31 = output capsule c.
template<int NCH, bool FIRST>
__global__ __launch_bounds__(256, 8)
void em_pass(const float* __restrict__ x,
             const float* __restrict__ a,
             const float* __restrict__ W,
             const float* __restrict__ bu,
             const float* __restrict__ ba,
             const float* __restrict__ part_r,
             float* __restrict__ part_w)
{
    constexpr int NCAP  = 288 / NCH;     // n's per chunk (72 for NCH=4)
    constexpr int NSTEP = NCAP / 8;      // 4 waves * 2 halves
    constexpr int SZ_S  = 576 * NCH * 32 * 16;

    __shared__ __align__(16) float pose_s[NCAP * 16];          // 4608 B
    __shared__ float ain_s[FIRST ? NCAP : 1];
    __shared__ float SA[2][32][17];                            // 4352 B
    __shared__ float SB[2][32][17];                            // 4352 B
    __shared__ float Rw[4][32];                                //  512 B
    __shared__ float mu_s[FIRST ? 1 : 32][17];
    __shared__ float p_s[FIRST ? 1 : 32][17];
    __shared__ float A_s[32];

    const int tid  = threadIdx.x;
    const int wv   = tid >> 6;
    const int lane = tid & 63;
    const int half = (lane >> 5) & 1;
    const int c    = lane & 31;

    const int pos = blockIdx.x;          // b*36 + oy*6 + ox
    const int ch  = blockIdx.y;
    const int b   = pos / 36;
    const int rem = pos % 36;
    const int oy  = rem / 6, ox = rem % 6;
    const int iy0 = oy * 2, ix0 = ox * 2;

    // ---- stage pose chunk (NCAP x 16 floats) into LDS ----
    {
        const float4* x4 = (const float4*)x;
        float4* d4 = (float4*)pose_s;
        for (int idx = tid; idx < NCAP * 4; idx += 256) {
            int n_l = idx >> 2, j = idx & 3;
            int n_g = ch * NCAP + n_l;
            int seg = n_g >> 5, bi = n_g & 31;
            int kh = seg / 3, kw = seg % 3;
            d4[idx] = x4[((b * 14 + iy0 + kh) * 14 + (ix0 + kw)) * 128 + bi * 4 + j];
        }
        if constexpr (FIRST) {
            for (int idx = tid; idx < NCAP; idx += 256) {
                int n_g = ch * NCAP + idx;
                int seg = n_g >> 5, bi = n_g & 31;
                int kh = seg / 3, kw = seg % 3;
                ain_s[idx] = a[((b * 14 + iy0 + kh) * 14 + (ix0 + kw)) * 32 + bi];
            }
        }
    }

    if constexpr (!FIRST) {
        // ---- fused finalize of the PREVIOUS pass's partials -> mu/p/A in LDS.
        // Redundant per chunk-block (tiny). thread = cf*8 + k2, handles il=k2,k2+8.
        const int cf = tid >> 3, k2 = tid & 7;
        float R = 0.f;
        #pragma unroll
        for (int q = 0; q < NCH; ++q)
            R += part_r[2 * SZ_S + (pos * NCH + q) * 32 + cf];
        float rinv = __fdividef(1.f, R + 1e-8f);
        float muv[2], pv[2];
        float tpart = 0.f;
        #pragma unroll
        for (int t2 = 0; t2 < 2; ++t2) {
            int k = k2 + t2 * 8;
            int base = ((pos * NCH) * 32 + cf) * 16 + k;
            float s1 = 0.f, s2 = 0.f;
            #pragma unroll
            for (int q = 0; q < NCH; ++q) {
                s1 += part_r[base + q * 512];
                s2 += part_r[SZ_S + base + q * 512];
            }
            float mu  = s1 * rinv;
            float sig = fmaf(-mu, mu, s2 * rinv);
            sig = fmaxf(sig, 1e-30f);
            muv[t2] = mu;
            pv[t2]  = __fdividef(0.5f, sig);
            tpart  += __logf(sig);
        }
        #pragma unroll
        for (int mk = 4; mk >= 1; mk >>= 1)
            tpart += __shfl_xor(tpart, mk);
        float cost = R * fmaf(0.5f, tpart, 16.f * bu[cf]);
        float aout = __fdividef(1.f, 1.f + __expf(-(0.001f * (ba[cf] - cost))));
        mu_s[cf][k2]     = muv[0];
        mu_s[cf][k2 + 8] = muv[1];
        p_s[cf][k2]      = pv[0];
        p_s[cf][k2 + 8]  = pv[1];
        if (k2 == 0)
            A_s[cf] = __logf(aout) - 0.5f * tpart - 8.0f * LN2PI;
    }
    __syncthreads();

    float muh[16], ph[16], Ac = 0.f;
    if constexpr (!FIRST) {
        #pragma unroll
        for (int il = 0; il < 16; ++il) { muh[il] = mu_s[c][il]; ph[il] = p_s[c][il]; }
        Ac = A_s[c];
    }

    float S1[16], S2[16], Racc = 0.f;
    #pragma unroll
    for (int i = 0; i < 16; ++i) { S1[i] = 0.f; S2[i] = 0.f; }

    // pointer-increment addressing: wp += 2 n * 32 c * 4 float4 per step
    const float4* wp = (const float4*)W +
        ((size_t)(ch * NCAP + wv * (NCAP / 4) + half) * 32 + c) * 4;
    const float4* pp = (const float4*)(pose_s + (wv * (NCAP / 4) + half) * 16);
    const float* an  = FIRST ? (ain_s + wv * (NCAP / 4) + half) : nullptr;

    for (int s = 0; s < NSTEP; ++s) {
        float wreg[16], preg[16];
        {
            float4 w0 = wp[0], w1 = wp[1], w2 = wp[2], w3 = wp[3];
            wreg[0]=w0.x; wreg[1]=w0.y; wreg[2]=w0.z; wreg[3]=w0.w;
            wreg[4]=w1.x; wreg[5]=w1.y; wreg[6]=w1.z; wreg[7]=w1.w;
            wreg[8]=w2.x; wreg[9]=w2.y; wreg[10]=w2.z; wreg[11]=w2.w;
            wreg[12]=w3.x; wreg[13]=w3.y; wreg[14]=w3.z; wreg[15]=w3.w;
            float4 p0 = pp[0], p1 = pp[1], p2 = pp[2], p3 = pp[3];
            preg[0]=p0.x; preg[1]=p0.y; preg[2]=p0.z; preg[3]=p0.w;
            preg[4]=p1.x; preg[5]=p1.y; preg[6]=p1.z; preg[7]=p1.w;
            preg[8]=p2.x; preg[9]=p2.y; preg[10]=p2.z; preg[11]=p2.w;
            preg[12]=p3.x; preg[13]=p3.y; preg[14]=p3.z; preg[15]=p3.w;
        }

        float v[16];
        #pragma unroll
        for (int i = 0; i < 4; ++i) {
            #pragma unroll
            for (int l = 0; l < 4; ++l) {
                float acc = preg[i*4+0] * wreg[l];
                acc = fmaf(preg[i*4+1], wreg[4 + l], acc);
                acc = fmaf(preg[i*4+2], wreg[8 + l], acc);
                acc = fmaf(preg[i*4+3], wreg[12 + l], acc);
                v[i*4+l] = acc;
            }
        }

        float r;
        if constexpr (FIRST) {
            r = an[2 * s] * 0.03125f;        // a_in / C
        } else {
            float acc = 0.0f;
            #pragma unroll
            for (int il = 0; il < 16; ++il) {
                float d = v[il] - muh[il];
                acc = fmaf(-ph[il], d * d, acc);
            }
            float lnap = Ac + acc;
            float m = lnap;
            #pragma unroll
            for (int mk = 16; mk >= 1; mk >>= 1)
                m = fmaxf(m, __shfl_xor(m, mk));
            float e = __expf(lnap - m);
            float ssum = e;
            #pragma unroll
            for (int mk = 16; mk >= 1; mk >>= 1)
                ssum += __shfl_xor(ssum, mk);
            r = __fdividef(e, ssum);
        }

        Racc += r;
        #pragma unroll
        for (int il = 0; il < 16; ++il) {
            float rv = r * v[il];
            S1[il] += rv;
            S2[il] = fmaf(rv, v[il], S2[il]);
        }

        wp += 256;      // 2 n * 32 c * 4 float4
        pp += 8;        // 2 n * 4 float4
    }

    // combine half-wave partials (same c, disjoint n) -> both halves hold totals
    #pragma unroll
    for (int il = 0; il < 16; ++il) {
        S1[il] += __shfl_xor(S1[il], 32);
        S2[il] += __shfl_xor(S2[il], 32);
    }
    Racc += __shfl_xor(Racc, 32);

    // two-phase half-split reduction: half0 owns S1 (SA), half1 owns S2 (SB)
    if (wv >= 2) {
        const int row = wv - 2;
        if (half == 0) {
            #pragma unroll
            for (int il = 0; il < 16; ++il) SA[row][c][il] = S1[il];
        } else {
            #pragma unroll
            for (int il = 0; il < 16; ++il) SB[row][c][il] = S2[il];
        }
    }
    if (half == 0) Rw[wv][c] = Racc;
    __syncthreads();
    if (wv < 2) {
        if (half == 0) {
            #pragma unroll
            for (int il = 0; il < 16; ++il) SA[wv][c][il] += S1[il];
        } else {
            #pragma unroll
            for (int il = 0; il < 16; ++il) SB[wv][c][il] += S2[il];
        }
    }
    __syncthreads();

    // write chunk partial to global
    for (int idx = tid; idx < 512; idx += 256) {
        int c2 = idx >> 4, k = idx & 15;
        float s1 = SA[0][c2][k] + SA[1][c2][k];
        float s2 = SB[0][c2][k] + SB[1][c2][k];
        size_t base = ((size_t)(pos * NCH + ch) * 32 + c2) * 16 + k;
        part_w[base]        = s1;
        part_w[SZ_S + base] = s2;
    }
    if (tid < 32)
        part_w[2 * (size_t)SZ_S + (pos * NCH + ch) * 32 + tid] =
            Rw[0][tid] + Rw[1][tid] + Rw[2][tid] + Rw[3][tid];
}

// ---------------- final output kernel ----------------
__global__ __launch_bounds__(256)
void em_out(const float* __restrict__ part_r,
            const float* __restrict__ bu,
            const float* __restrict__ ba,
            float* __restrict__ out, int nch)
{
    const int pos = blockIdx.x;
    const int tid = threadIdx.x;
    const int cf = tid >> 3, k2 = tid & 7;
    const int SZ_S = 576 * nch * 512;

    float R = 0.f;
    for (int q = 0; q < nch; ++q)
        R += part_r[2 * (size_t)SZ_S + (pos * nch + q) * 32 + cf];
    float rinv = __fdividef(1.f, R + 1e-8f);
    float muv[2];
    float tpart = 0.f;
    #pragma unroll
    for (int t2 = 0; t2 < 2; ++t2) {
        int k = k2 + t2 * 8;
        int base = ((pos * nch) * 32 + cf) * 16 + k;
        float s1 = 0.f, s2 = 0.f;
        for (int q = 0; q < nch; ++q) {
            s1 += part_r[base + q * 512];
            s2 += part_r[SZ_S + base + q * 512];
        }
        float mu  = s1 * rinv;
        float sig = fmaf(-mu, mu, s2 * rinv);
        sig = fmaxf(sig, 1e-30f);
        muv[t2] = mu;
        tpart  += __logf(sig);
    }
    #pragma unroll
    for (int mk = 4; mk >= 1; mk >>= 1)
        tpart += __shfl_xor(tpart, mk);
    float cost = R * fmaf(0.5f, tpart, 16.f * bu[cf]);
    float aout = __fdividef(1.f, 1.f + __expf(-(0.001f * (ba[cf] - cost))));

    out[(size_t)pos * 512 + cf * 16 + k2]     = muv[0];
    out[(size_t)pos * 512 + cf * 16 + k2 + 8] = muv[1];
    if (k2 == 0)
        out[294912 + pos * 32 + cf] = aout;
}

// ---------------- legacy single-kernel fallback (R1, known-good 107us) ----------------
#define NB 288
#define LNSTEP 36
__global__ __launch_bounds__(256, 2)
void convcaps_em_legacy(const float* __restrict__ x, const float* __restrict__ a,
                        const float* __restrict__ W, const float* __restrict__ bu,
                        const float* __restrict__ ba, float* __restrict__ out)
{
    __shared__ __align__(16) float pose_s[NB * 16];
    __shared__ __align__(16) float ain_s[NB];
    __shared__ float S1w[4][32][17];
    __shared__ float S2w[4][32][17];
    __shared__ float Rw[4][32];
    __shared__ float mu_s[32][17];
    __shared__ float p_s[32][17];
    __shared__ float A_s[32];

    const int tid = threadIdx.x, wv = tid >> 6, lane = tid & 63;
    const int half = (lane >> 5) & 1, c = lane & 31;
    const int bid = blockIdx.x, b = bid / 36, rem = bid % 36;
    const int oy = rem / 6, ox = rem % 6, iy0 = oy * 2, ix0 = ox * 2;
    {
        const float4* x4 = (const float4*)x;
        float4* d4 = (float4*)pose_s;
        for (int idx = tid; idx < 1152; idx += 256) {
            int seg = idx >> 7, u = idx & 127, kh = seg / 3, kw = seg % 3;
            d4[idx] = x4[((b * 14 + iy0 + kh) * 14 + (ix0 + kw)) * 128 + u];
        }
        const float4* a4 = (const float4*)a;
        float4* e4 = (float4*)ain_s;
        if (tid < 72) {
            int seg = tid >> 3, u = tid & 7, kh = seg / 3, kw = seg % 3;
            e4[tid] = a4[((b * 14 + iy0 + kh) * 14 + (ix0 + kw)) * 8 + u];
        }
    }
    __syncthreads();
    const float4* W4 = (const float4*)W;
    float muh[16], ph[16], Ac = 0.0f;
    #pragma unroll
    for (int i = 0; i < 16; ++i) { muh[i] = 0.0f; ph[i] = 0.0f; }
    for (int iter = 0; iter < 3; ++iter) {
        if (iter > 0) {
            #pragma unroll
            for (int il = 0; il < 16; ++il) { muh[il] = mu_s[c][il]; ph[il] = p_s[c][il]; }
            Ac = A_s[c];
        }
        float S1[16], S2[16], Racc = 0.0f;
        #pragma unroll
        for (int i = 0; i < 16; ++i) { S1[i] = 0.0f; S2[i] = 0.0f; }
        for (int s = 0; s < LNSTEP; ++s) {
            const int n = wv * 72 + 2 * s + half;
            float wreg[16], preg[16];
            const float4* wp = W4 + (size_t)(n * 32 + c) * 4;
            float4 w0 = wp[0], w1 = wp[1], w2 = wp[2], w3 = wp[3];
            wreg[0]=w0.x; wreg[1]=w0.y; wreg[2]=w0.z; wreg[3]=w0.w;
            wreg[4]=w1.x; wreg[5]=w1.y; wreg[6]=w1.z; wreg[7]=w1.w;
            wreg[8]=w2.x; wreg[9]=w2.y; wreg[10]=w2.z; wreg[11]=w2.w;
            wreg[12]=w3.x; wreg[13]=w3.y; wreg[14]=w3.z; wreg[15]=w3.w;
            const float4* pp = (const float4*)&pose_s[n * 16];
            float4 p0 = pp[0], p1 = pp[1], p2 = pp[2], p3 = pp[3];
            preg[0]=p0.x; preg[1]=p0.y; preg[2]=p0.z; preg[3]=p0.w;
            preg[4]=p1.x; preg[5]=p1.y; preg[6]=p1.z; preg[7]=p1.w;
            preg[8]=p2.x; preg[9]=p2.y; preg[10]=p2.z; preg[11]=p2.w;
            preg[12]=p3.x; preg[13]=p3.y; preg[14]=p3.z; preg[15]=p3.w;
            float v[16];
            #pragma unroll
            for (int i = 0; i < 4; ++i)
                #pragma unroll
                for (int l = 0; l < 4; ++l) {
                    float acc = preg[i*4+0] * wreg[l];
                    acc = fmaf(preg[i*4+1], wreg[4+l], acc);
                    acc = fmaf(preg[i*4+2], wreg[8+l], acc);
                    acc = fmaf(preg[i*4+3], wreg[12+l], acc);
                    v[i*4+l] = acc;
                }
            float r;
            if (iter == 0) r = ain_s[n] * 0.03125f;
            else {
                float acc = 0.0f;
                #pragma unroll
                for (int il = 0; il < 16; ++il) { float d = v[il]-muh[il]; acc = fmaf(-ph[il], d*d, acc); }
                float lnap = Ac + acc, m = lnap;
                #pragma unroll
                for (int mk = 16; mk >= 1; mk >>= 1) m = fmaxf(m, __shfl_xor(m, mk));
                float e = __expf(lnap - m), ssum = e;
                #pragma unroll
                for (int mk = 16; mk >= 1; mk >>= 1) ssum += __shfl_xor(ssum, mk);
                r = __fdividef(e, ssum);
            }
            Racc += r;
            #pragma unroll
            for (int il = 0; il < 16; ++il) { float rv = r * v[il]; S1[il] += rv; S2[il] = fmaf(rv, v[il], S2[il]); }
        }
        #pragma unroll
        for (int il = 0; il < 16; ++il) { S1[il] += __shfl_xor(S1[il], 32); S2[il] += __shfl_xor(S2[il], 32); }
        Racc += __shfl_xor(Racc, 32);
        if (half == 0) {
            #pragma unroll
            for (int il = 0; il < 16; ++il) { S1w[wv][c][il] = S1[il]; S2w[wv][c][il] = S2[il]; }
            Rw[wv][c] = Racc;
        }
        __syncthreads();
        {
            const int c2 = tid >> 3, k = tid & 7;
            float R = Rw[0][c2] + Rw[1][c2] + Rw[2][c2] + Rw[3][c2];
            float rinv = __fdividef(1.0f, R + 1e-8f);
            float muv[2], pv[2], tpart = 0.0f;
            #pragma unroll
            for (int t2 = 0; t2 < 2; ++t2) {
                int il = k + t2 * 8;
                float s1 = S1w[0][c2][il]+S1w[1][c2][il]+S1w[2][c2][il]+S1w[3][c2][il];
                float s2 = S2w[0][c2][il]+S2w[1][c2][il]+S2w[2][c2][il]+S2w[3][c2][il];
                float mu = s1 * rinv;
                float sig = fmaf(-mu, mu, s2 * rinv);
                sig = fmaxf(sig, 1e-30f);
                muv[t2] = mu; pv[t2] = __fdividef(0.5f, sig); tpart += __logf(sig);
            }
            #pragma unroll
            for (int mk = 4; mk >= 1; mk >>= 1) tpart += __shfl_xor(tpart, mk);
            float cost = R * fmaf(0.5f, tpart, 16.0f * bu[c2]);
            float aout = __fdividef(1.0f, 1.0f + __expf(-(0.001f * (ba[c2] - cost))));
            if (iter < 2) {
                #pragma unroll
                for (int t2 = 0; t2 < 2; ++t2) { int il = k + t2*8; mu_s[c2][il] = muv[t2]; p_s[c2][il] = pv[t2]; }
                if (k == 0) A_s[c2] = __logf(aout) - 0.5f * tpart - 8.0f * LN2PI;
            } else {
                #pragma unroll
                for (int t2 = 0; t2 < 2; ++t2) { int il = k + t2*8; out[(size_t)bid*512 + c2*16 + il] = muv[t2]; }
                if (k == 0) out[294912 + bid * 32 + c2] = aout;
            }
        }
        __syncthreads();
    }
}

// ---------------- host ----------------
template<int NCH>
static void run_split(const float* x, const float* a, const float* w,
                      const float* bu, const float* ba, float* out,
                      float* wsf, hipStream_t stream)
{
    const size_t bufN = (size_t)576 * NCH * 32 * 33;   // floats per parity buffer
    float* buf0 = wsf;
    float* buf1 = wsf + bufN;
    hipLaunchKernelGGL((em_pass<NCH, true>),  dim3(576, NCH), dim3(256), 0, stream,
                       x, a, w, bu, ba, (const float*)nullptr, buf0);
    hipLaunchKernelGGL((em_pass<NCH, false>), dim3(576, NCH), dim3(256), 0, stream,
                       x, a, w, bu, ba, buf0, buf1);
    hipLaunchKernelGGL((em_pass<NCH, false>), dim3(576, NCH), dim3(256), 0, stream,
                       x, a, w, bu, ba, buf1, buf0);
    hipLaunchKernelGGL(em_out, dim3(576), dim3(256), 0, stream, buf0, bu, ba, out, NCH);
}

extern "C" void kernel_launch(void* const* d_in, const int* in_sizes, int n_in,
                              void* d_out, int out_size, void* d_ws, size_t ws_size,
                              hipStream_t stream) {
    (void)in_sizes; (void)n_in; (void)out_size;
    const float* x  = (const float*)d_in[0];
    const float* a  = (const float*)d_in[1];
    const float* w  = (const float*)d_in[2];
    const float* bu = (const float*)d_in[3];
    const float* ba = (const float*)d_in[4];
    float* out = (float*)d_out;
    float* wsf = (float*)d_ws;

    auto need = [](int nch) -> size_t { return (size_t)2 * 576 * nch * 32 * 33 * 4; };

    if (ws_size >= need(4))      run_split<4>(x, a, w, bu, ba, out, wsf, stream);
    else if (ws_size >= need(2)) run_split<2>(x, a, w, bu, ba, out, wsf, stream);
    else if (ws_size >= need(1)) run_split<1>(x, a, w, bu, ba, out, wsf, stream);
    else
        hipLaunchKernelGGL(convcaps_em_legacy, dim3(576), dim3(256), 0, stream,
                           x, a, w, bu, ba, out);
}

// Round 6
// 128.082 us; speedup vs baseline: 4.4303x; 4.4303x over previous
//
#include <hip/hip_runtime.h>

// ConvCaps EM routing, MI355X — multi-dispatch, occupancy-tuned.
// Geometry: b=16 -> 576 positions; N=288 input caps; C=32; ITERS=3.
//
// R1  fused 4-wave:  107us (VALUBusy 40%, Occ 20% — grid-limited).
// R4  NCH=4 split:   123us; E-pass 53.7us, Occ 31%, LDS 27KB -> 5 blocks/CU.
// R2/R5 lesson: __launch_bounds__ min-waves (6 or 8) caps VGPR (40/32) ->
//   total spill (FETCH 460/511MB). NEVER cap below natural (~60 VGPR).
// R6: NCH=6 (3456 blocks, NSTEP=6), natural VGPR, half-split reduce scratch
//   (LDS ~17KB -> 8 blocks/CU by wave cap), per-step softmax max-tree removed
//   (M = max_c Ac hoisted once per pass; exp(lnap-M) <= 1 by construction).

#define LN2PI 1.8378770664093453f

// ---------------- M-pass kernel ----------------
// grid (576, NCH), block 256 (4 waves). pos=blockIdx.x, chunk=blockIdx.y.
// Each half-wave owns one n per step; lane&31 = output capsule c.
template<int NCH, bool FIRST>
__global__ __launch_bounds__(256)
void em_pass(const float* __restrict__ x,
             const float* __restrict__ a,
             const float* __restrict__ W,
             const float* __restrict__ bu,
             const float* __restrict__ ba,
             const float* __restrict__ part_r,
             float* __restrict__ part_w)
{
    constexpr int NCAP  = 288 / NCH;     // n's per chunk (48 for NCH=6)
    constexpr int NSTEP = NCAP / 8;      // 4 waves * 2 halves
    constexpr int SZ_S  = 576 * NCH * 32 * 16;

    __shared__ __align__(16) float pose_s[NCAP * 16];
    __shared__ float ain_s[FIRST ? NCAP : 1];
    __shared__ float SA[2][32][17];                  // half-split reduce scratch
    __shared__ float SB[2][32][17];
    __shared__ float Rw[4][32];
    __shared__ float mu_s[FIRST ? 1 : 32][17];
    __shared__ float p_s[FIRST ? 1 : 32][17];
    __shared__ float A_s[32];

    const int tid  = threadIdx.x;
    const int wv   = tid >> 6;
    const int lane = tid & 63;
    const int half = (lane >> 5) & 1;
    const int c    = lane & 31;

    const int pos = blockIdx.x;          // b*36 + oy*6 + ox
    const int ch  = blockIdx.y;
    const int b   = pos / 36;
    const int rem = pos % 36;
    const int oy  = rem / 6, ox = rem % 6;
    const int iy0 = oy * 2, ix0 = ox * 2;

    // ---- stage pose chunk (NCAP x 16 floats) into LDS ----
    {
        const float4* x4 = (const float4*)x;
        float4* d4 = (float4*)pose_s;
        for (int idx = tid; idx < NCAP * 4; idx += 256) {
            int n_l = idx >> 2, j = idx & 3;
            int n_g = ch * NCAP + n_l;
            int seg = n_g >> 5, bi = n_g & 31;
            int kh = seg / 3, kw = seg % 3;
            d4[idx] = x4[((b * 14 + iy0 + kh) * 14 + (ix0 + kw)) * 128 + bi * 4 + j];
        }
        if constexpr (FIRST) {
            for (int idx = tid; idx < NCAP; idx += 256) {
                int n_g = ch * NCAP + idx;
                int seg = n_g >> 5, bi = n_g & 31;
                int kh = seg / 3, kw = seg % 3;
                ain_s[idx] = a[((b * 14 + iy0 + kh) * 14 + (ix0 + kw)) * 32 + bi];
            }
        }
    }

    if constexpr (!FIRST) {
        // ---- fused finalize of the PREVIOUS pass's partials -> mu/p/A in LDS.
        // Redundant per chunk-block (tiny). thread = cf*8 + k2, handles il=k2,k2+8.
        const int cf = tid >> 3, k2 = tid & 7;
        float R = 0.f;
        #pragma unroll
        for (int q = 0; q < NCH; ++q)
            R += part_r[2 * SZ_S + (pos * NCH + q) * 32 + cf];
        float rinv = __fdividef(1.f, R + 1e-8f);
        float muv[2], pv[2];
        float tpart = 0.f;
        #pragma unroll
        for (int t2 = 0; t2 < 2; ++t2) {
            int k = k2 + t2 * 8;
            int base = ((pos * NCH) * 32 + cf) * 16 + k;
            float s1 = 0.f, s2 = 0.f;
            #pragma unroll
            for (int q = 0; q < NCH; ++q) {
                s1 += part_r[base + q * 512];
                s2 += part_r[SZ_S + base + q * 512];
            }
            float mu  = s1 * rinv;
            float sig = fmaf(-mu, mu, s2 * rinv);
            sig = fmaxf(sig, 1e-30f);
            muv[t2] = mu;
            pv[t2]  = __fdividef(0.5f, sig);
            tpart  += __logf(sig);
        }
        #pragma unroll
        for (int mk = 4; mk >= 1; mk >>= 1)
            tpart += __shfl_xor(tpart, mk);
        float cost = R * fmaf(0.5f, tpart, 16.f * bu[cf]);
        float aout = __fdividef(1.f, 1.f + __expf(-(0.001f * (ba[cf] - cost))));
        mu_s[cf][k2]     = muv[0];
        mu_s[cf][k2 + 8] = muv[1];
        p_s[cf][k2]      = pv[0];
        p_s[cf][k2 + 8]  = pv[1];
        if (k2 == 0)
            A_s[cf] = __logf(aout) - 0.5f * tpart - 8.0f * LN2PI;
    }
    __syncthreads();

    float muh[16], ph[16], Ac = 0.f;
    if constexpr (!FIRST) {
        #pragma unroll
        for (int il = 0; il < 16; ++il) { muh[il] = mu_s[c][il]; ph[il] = p_s[c][il]; }
        // hoisted softmax guard: Ac' = A_c - max_c A_c  (<= 0), so per-step
        // lnap' = Ac' - sum p d^2 <= 0 -> exp never overflows; max tree removed
        // from the n-loop (was 5 DS ops/step).
        float A = A_s[c];
        float m = A;
        #pragma unroll
        for (int mk = 16; mk >= 1; mk >>= 1)
            m = fmaxf(m, __shfl_xor(m, mk));
        Ac = A - m;
    }

    float S1[16], S2[16], Racc = 0.f;
    #pragma unroll
    for (int i = 0; i < 16; ++i) { S1[i] = 0.f; S2[i] = 0.f; }

    // pointer-increment addressing: wp += 2 n * 32 c * 4 float4 per step
    const float4* wp = (const float4*)W +
        ((size_t)(ch * NCAP + wv * (NCAP / 4) + half) * 32 + c) * 4;
    const float4* pp = (const float4*)(pose_s + (wv * (NCAP / 4) + half) * 16);
    const float* an  = FIRST ? (ain_s + wv * (NCAP / 4) + half) : nullptr;

    for (int s = 0; s < NSTEP; ++s) {
        float wreg[16], preg[16];
        {
            float4 w0 = wp[0], w1 = wp[1], w2 = wp[2], w3 = wp[3];
            wreg[0]=w0.x; wreg[1]=w0.y; wreg[2]=w0.z; wreg[3]=w0.w;
            wreg[4]=w1.x; wreg[5]=w1.y; wreg[6]=w1.z; wreg[7]=w1.w;
            wreg[8]=w2.x; wreg[9]=w2.y; wreg[10]=w2.z; wreg[11]=w2.w;
            wreg[12]=w3.x; wreg[13]=w3.y; wreg[14]=w3.z; wreg[15]=w3.w;
            float4 p0 = pp[0], p1 = pp[1], p2 = pp[2], p3 = pp[3];
            preg[0]=p0.x; preg[1]=p0.y; preg[2]=p0.z; preg[3]=p0.w;
            preg[4]=p1.x; preg[5]=p1.y; preg[6]=p1.z; preg[7]=p1.w;
            preg[8]=p2.x; preg[9]=p2.y; preg[10]=p2.z; preg[11]=p2.w;
            preg[12]=p3.x; preg[13]=p3.y; preg[14]=p3.z; preg[15]=p3.w;
        }

        float v[16];
        #pragma unroll
        for (int i = 0; i < 4; ++i) {
            #pragma unroll
            for (int l = 0; l < 4; ++l) {
                float acc = preg[i*4+0] * wreg[l];
                acc = fmaf(preg[i*4+1], wreg[4 + l], acc);
                acc = fmaf(preg[i*4+2], wreg[8 + l], acc);
                acc = fmaf(preg[i*4+3], wreg[12 + l], acc);
                v[i*4+l] = acc;
            }
        }

        float r;
        if constexpr (FIRST) {
            r = an[2 * s] * 0.03125f;        // a_in / C
        } else {
            float acc = Ac;                  // already max-subtracted, <= 0
            #pragma unroll
            for (int il = 0; il < 16; ++il) {
                float d = v[il] - muh[il];
                acc = fmaf(-ph[il], d * d, acc);
            }
            float e = __expf(acc);           // e <= 1, no overflow
            float ssum = e;
            #pragma unroll
            for (int mk = 16; mk >= 1; mk >>= 1)
                ssum += __shfl_xor(ssum, mk);
            r = __fdividef(e, ssum + 1e-37f);
        }

        Racc += r;
        #pragma unroll
        for (int il = 0; il < 16; ++il) {
            float rv = r * v[il];
            S1[il] += rv;
            S2[il] = fmaf(rv, v[il], S2[il]);
        }

        wp += 256;      // 2 n * 32 c * 4 float4
        pp += 8;        // 2 n * 4 float4
    }

    // combine half-wave partials (same c, disjoint n) -> both halves hold totals
    #pragma unroll
    for (int il = 0; il < 16; ++il) {
        S1[il] += __shfl_xor(S1[il], 32);
        S2[il] += __shfl_xor(S2[il], 32);
    }
    Racc += __shfl_xor(Racc, 32);

    // two-phase half-split reduction: half0 owns S1 (SA), half1 owns S2 (SB)
    if (wv >= 2) {
        const int row = wv - 2;
        if (half == 0) {
            #pragma unroll
            for (int il = 0; il < 16; ++il) SA[row][c][il] = S1[il];
        } else {
            #pragma unroll
            for (int il = 0; il < 16; ++il) SB[row][c][il] = S2[il];
        }
    }
    if (half == 0) Rw[wv][c] = Racc;
    __syncthreads();
    if (wv < 2) {
        if (half == 0) {
            #pragma unroll
            for (int il = 0; il < 16; ++il) SA[wv][c][il] += S1[il];
        } else {
            #pragma unroll
            for (int il = 0; il < 16; ++il) SB[wv][c][il] += S2[il];
        }
    }
    __syncthreads();

    // write chunk partial to global
    for (int idx = tid; idx < 512; idx += 256) {
        int c2 = idx >> 4, k = idx & 15;
        float s1 = SA[0][c2][k] + SA[1][c2][k];
        float s2 = SB[0][c2][k] + SB[1][c2][k];
        size_t base = ((size_t)(pos * NCH + ch) * 32 + c2) * 16 + k;
        part_w[base]        = s1;
        part_w[SZ_S + base] = s2;
    }
    if (tid < 32)
        part_w[2 * (size_t)SZ_S + (pos * NCH + ch) * 32 + tid] =
            Rw[0][tid] + Rw[1][tid] + Rw[2][tid] + Rw[3][tid];
}

// ---------------- final output kernel ----------------
__global__ __launch_bounds__(256)
void em_out(const float* __restrict__ part_r,
            const float* __restrict__ bu,
            const float* __restrict__ ba,
            float* __restrict__ out, int nch)
{
    const int pos = blockIdx.x;
    const int tid = threadIdx.x;
    const int cf = tid >> 3, k2 = tid & 7;
    const int SZ_S = 576 * nch * 512;

    float R = 0.f;
    for (int q = 0; q < nch; ++q)
        R += part_r[2 * (size_t)SZ_S + (pos * nch + q) * 32 + cf];
    float rinv = __fdividef(1.f, R + 1e-8f);
    float muv[2];
    float tpart = 0.f;
    #pragma unroll
    for (int t2 = 0; t2 < 2; ++t2) {
        int k = k2 + t2 * 8;
        int base = ((pos * nch) * 32 + cf) * 16 + k;
        float s1 = 0.f, s2 = 0.f;
        for (int q = 0; q < nch; ++q) {
            s1 += part_r[base + q * 512];
            s2 += part_r[SZ_S + base + q * 512];
        }
        float mu  = s1 * rinv;
        float sig = fmaf(-mu, mu, s2 * rinv);
        sig = fmaxf(sig, 1e-30f);
        muv[t2] = mu;
        tpart  += __logf(sig);
    }
    #pragma unroll
    for (int mk = 4; mk >= 1; mk >>= 1)
        tpart += __shfl_xor(tpart, mk);
    float cost = R * fmaf(0.5f, tpart, 16.f * bu[cf]);
    float aout = __fdividef(1.f, 1.f + __expf(-(0.001f * (ba[cf] - cost))));

    out[(size_t)pos * 512 + cf * 16 + k2]     = muv[0];
    out[(size_t)pos * 512 + cf * 16 + k2 + 8] = muv[1];
    if (k2 == 0)
        out[294912 + pos * 32 + cf] = aout;
}

// ---------------- legacy single-kernel fallback (R1, known-good 107us) ----------------
#define NB 288
#define LNSTEP 36
__global__ __launch_bounds__(256, 2)
void convcaps_em_legacy(const float* __restrict__ x, const float* __restrict__ a,
                        const float* __restrict__ W, const float* __restrict__ bu,
                        const float* __restrict__ ba, float* __restrict__ out)
{
    __shared__ __align__(16) float pose_s[NB * 16];
    __shared__ __align__(16) float ain_s[NB];
    __shared__ float S1w[4][32][17];
    __shared__ float S2w[4][32][17];
    __shared__ float Rw[4][32];
    __shared__ float mu_s[32][17];
    __shared__ float p_s[32][17];
    __shared__ float A_s[32];

    const int tid = threadIdx.x, wv = tid >> 6, lane = tid & 63;
    const int half = (lane >> 5) & 1, c = lane & 31;
    const int bid = blockIdx.x, b = bid / 36, rem = bid % 36;
    const int oy = rem / 6, ox = rem % 6, iy0 = oy * 2, ix0 = ox * 2;
    {
        const float4* x4 = (const float4*)x;
        float4* d4 = (float4*)pose_s;
        for (int idx = tid; idx < 1152; idx += 256) {
            int seg = idx >> 7, u = idx & 127, kh = seg / 3, kw = seg % 3;
            d4[idx] = x4[((b * 14 + iy0 + kh) * 14 + (ix0 + kw)) * 128 + u];
        }
        const float4* a4 = (const float4*)a;
        float4* e4 = (float4*)ain_s;
        if (tid < 72) {
            int seg = tid >> 3, u = tid & 7, kh = seg / 3, kw = seg % 3;
            e4[tid] = a4[((b * 14 + iy0 + kh) * 14 + (ix0 + kw)) * 8 + u];
        }
    }
    __syncthreads();
    const float4* W4 = (const float4*)W;
    float muh[16], ph[16], Ac = 0.0f;
    #pragma unroll
    for (int i = 0; i < 16; ++i) { muh[i] = 0.0f; ph[i] = 0.0f; }
    for (int iter = 0; iter < 3; ++iter) {
        if (iter > 0) {
            #pragma unroll
            for (int il = 0; il < 16; ++il) { muh[il] = mu_s[c][il]; ph[il] = p_s[c][il]; }
            Ac = A_s[c];
        }
        float S1[16], S2[16], Racc = 0.0f;
        #pragma unroll
        for (int i = 0; i < 16; ++i) { S1[i] = 0.0f; S2[i] = 0.0f; }
        for (int s = 0; s < LNSTEP; ++s) {
            const int n = wv * 72 + 2 * s + half;
            float wreg[16], preg[16];
            const float4* wp = W4 + (size_t)(n * 32 + c) * 4;
            float4 w0 = wp[0], w1 = wp[1], w2 = wp[2], w3 = wp[3];
            wreg[0]=w0.x; wreg[1]=w0.y; wreg[2]=w0.z; wreg[3]=w0.w;
            wreg[4]=w1.x; wreg[5]=w1.y; wreg[6]=w1.z; wreg[7]=w1.w;
            wreg[8]=w2.x; wreg[9]=w2.y; wreg[10]=w2.z; wreg[11]=w2.w;
            wreg[12]=w3.x; wreg[13]=w3.y; wreg[14]=w3.z; wreg[15]=w3.w;
            const float4* pp = (const float4*)&pose_s[n * 16];
            float4 p0 = pp[0], p1 = pp[1], p2 = pp[2], p3 = pp[3];
            preg[0]=p0.x; preg[1]=p0.y; preg[2]=p0.z; preg[3]=p0.w;
            preg[4]=p1.x; preg[5]=p1.y; preg[6]=p1.z; preg[7]=p1.w;
            preg[8]=p2.x; preg[9]=p2.y; preg[10]=p2.z; preg[11]=p2.w;
            preg[12]=p3.x; preg[13]=p3.y; preg[14]=p3.z; preg[15]=p3.w;
            float v[16];
            #pragma unroll
            for (int i = 0; i < 4; ++i)
                #pragma unroll
                for (int l = 0; l < 4; ++l) {
                    float acc = preg[i*4+0] * wreg[l];
                    acc = fmaf(preg[i*4+1], wreg[4+l], acc);
                    acc = fmaf(preg[i*4+2], wreg[8+l], acc);
                    acc = fmaf(preg[i*4+3], wreg[12+l], acc);
                    v[i*4+l] = acc;
                }
            float r;
            if (iter == 0) r = ain_s[n] * 0.03125f;
            else {
                float acc = 0.0f;
                #pragma unroll
                for (int il = 0; il < 16; ++il) { float d = v[il]-muh[il]; acc = fmaf(-ph[il], d*d, acc); }
                float lnap = Ac + acc, m = lnap;
                #pragma unroll
                for (int mk = 16; mk >= 1; mk >>= 1) m = fmaxf(m, __shfl_xor(m, mk));
                float e = __expf(lnap - m), ssum = e;
                #pragma unroll
                for (int mk = 16; mk >= 1; mk >>= 1) ssum += __shfl_xor(ssum, mk);
                r = __fdividef(e, ssum);
            }
            Racc += r;
            #pragma unroll
            for (int il = 0; il < 16; ++il) { float rv = r * v[il]; S1[il] += rv; S2[il] = fmaf(rv, v[il], S2[il]); }
        }
        #pragma unroll
        for (int il = 0; il < 16; ++il) { S1[il] += __shfl_xor(S1[il], 32); S2[il] += __shfl_xor(S2[il], 32); }
        Racc += __shfl_xor(Racc, 32);
        if (half == 0) {
            #pragma unroll
            for (int il = 0; il < 16; ++il) { S1w[wv][c][il] = S1[il]; S2w[wv][c][il] = S2[il]; }
            Rw[wv][c] = Racc;
        }
        __syncthreads();
        {
            const int c2 = tid >> 3, k = tid & 7;
            float R = Rw[0][c2] + Rw[1][c2] + Rw[2][c2] + Rw[3][c2];
            float rinv = __fdividef(1.0f, R + 1e-8f);
            float muv[2], pv[2], tpart = 0.0f;
            #pragma unroll
            for (int t2 = 0; t2 < 2; ++t2) {
                int il = k + t2 * 8;
                float s1 = S1w[0][c2][il]+S1w[1][c2][il]+S1w[2][c2][il]+S1w[3][c2][il];
                float s2 = S2w[0][c2][il]+S2w[1][c2][il]+S2w[2][c2][il]+S2w[3][c2][il];
                float mu = s1 * rinv;
                float sig = fmaf(-mu, mu, s2 * rinv);
                sig = fmaxf(sig, 1e-30f);
                muv[t2] = mu; pv[t2] = __fdividef(0.5f, sig); tpart += __logf(sig);
            }
            #pragma unroll
            for (int mk = 4; mk >= 1; mk >>= 1) tpart += __shfl_xor(tpart, mk);
            float cost = R * fmaf(0.5f, tpart, 16.0f * bu[c2]);
            float aout = __fdividef(1.0f, 1.0f + __expf(-(0.001f * (ba[c2] - cost))));
            if (iter < 2) {
                #pragma unroll
                for (int t2 = 0; t2 < 2; ++t2) { int il = k + t2*8; mu_s[c2][il] = muv[t2]; p_s[c2][il] = pv[t2]; }
                if (k == 0) A_s[c2] = __logf(aout) - 0.5f * tpart - 8.0f * LN2PI;
            } else {
                #pragma unroll
                for (int t2 = 0; t2 < 2; ++t2) { int il = k + t2*8; out[(size_t)bid*512 + c2*16 + il] = muv[t2]; }
                if (k == 0) out[294912 + bid * 32 + c2] = aout;
            }
        }
        __syncthreads();
    }
}

// ---------------- host ----------------
template<int NCH>
static void run_split(const float* x, const float* a, const float* w,
                      const float* bu, const float* ba, float* out,
                      float* wsf, hipStream_t stream)
{
    const size_t bufN = (size_t)576 * NCH * 32 * 33;   // floats per parity buffer
    float* buf0 = wsf;
    float* buf1 = wsf + bufN;
    hipLaunchKernelGGL((em_pass<NCH, true>),  dim3(576, NCH), dim3(256), 0, stream,
                       x, a, w, bu, ba, (const float*)nullptr, buf0);
    hipLaunchKernelGGL((em_pass<NCH, false>), dim3(576, NCH), dim3(256), 0, stream,
                       x, a, w, bu, ba, buf0, buf1);
    hipLaunchKernelGGL((em_pass<NCH, false>), dim3(576, NCH), dim3(256), 0, stream,
                       x, a, w, bu, ba, buf1, buf0);
    hipLaunchKernelGGL(em_out, dim3(576), dim3(256), 0, stream, buf0, bu, ba, out, NCH);
}

extern "C" void kernel_launch(void* const* d_in, const int* in_sizes, int n_in,
                              void* d_out, int out_size, void* d_ws, size_t ws_size,
                              hipStream_t stream) {
    (void)in_sizes; (void)n_in; (void)out_size;
    const float* x  = (const float*)d_in[0];
    const float* a  = (const float*)d_in[1];
    const float* w  = (const float*)d_in[2];
    const float* bu = (const float*)d_in[3];
    const float* ba = (const float*)d_in[4];
    float* out = (float*)d_out;
    float* wsf = (float*)d_ws;

    auto need = [](int nch) -> size_t { return (size_t)2 * 576 * nch * 32 * 33 * 4; };

    if (ws_size >= need(6))      run_split<6>(x, a, w, bu, ba, out, wsf, stream);
    else if (ws_size >= need(4)) run_split<4>(x, a, w, bu, ba, out, wsf, stream);
    else if (ws_size >= need(2)) run_split<2>(x, a, w, bu, ba, out, wsf, stream);
    else
        hipLaunchKernelGGL(convcaps_em_legacy, dim3(576), dim3(256), 0, stream,
                           x, a, w, bu, ba, out);
}

// Round 8
// 115.289 us; speedup vs baseline: 4.9219x; 1.1110x over previous
//
#include <hip/hip_runtime.h>

// ConvCaps EM routing, MI355X — multi-dispatch (stream order = iteration sync).
// Geometry: b=16 -> 576 positions; N=288 input caps; C=32; ITERS=3.
//
// R1 fused: 107us. R4/R6 split: ~128us, E-pass 54.8us, VALUBusy 47%, Occ 33%.
// R2/R5: min-waves launch_bounds FAR below natural VGPR -> total spill. R7:
// cooperative grid.sync hung (co-residency not honored) -> never again.
// R8: (a) W transposed once into ws -> coalesced dwordx4 (was stride-64B
//     gather, 32 lines/inst -> 8); (b) launch_bounds(256,4) cap=128 ~= demand
//     (~120) so hoisted state stays in VGPRs (R6's 60-VGPR build demoted
//     muh/ph to ~32 LDS rereads/step); (c) packed dual-FP32 (f32x2 ->
//     v_pk_fma_f32) across v-compute/E-step/accumulate; E-step algebra folded
//     (t=fma(-p,v,2pmu); acc=fma(t,v,acc); sum p*mu^2 folded into A).

#define LN2PI 1.8378770664093453f

typedef __attribute__((ext_vector_type(2))) float f32x2;
#define FMA2(a, b, c) __builtin_elementwise_fma((a), (b), (c))
__device__ __forceinline__ f32x2 splat2(float x) { f32x2 r; r.x = x; r.y = x; return r; }

// DPP butterfly add over 32-lane group (never crosses the half-wave boundary).
#define DPP_ADD(x, ctrl) \
    ((x) + __int_as_float(__builtin_amdgcn_update_dpp( \
        0, __float_as_int(x), (ctrl), 0xF, 0xF, true)))

__device__ __forceinline__ float sum32(float e) {
    float s = e;
    s = DPP_ADD(s, 0xB1);   // quad_perm(1,0,3,2): xor1
    s = DPP_ADD(s, 0x4E);   // quad_perm(2,3,0,1): xor2
    s = DPP_ADD(s, 0x141);  // row_half_mirror: xor4 (groups of 4 equal)
    s = DPP_ADD(s, 0x140);  // row_mirror:      xor8 (groups of 8 equal)
    s += __shfl_xor(s, 16);
    return s;
}

// ---------------- W transpose: W[n][c][q] -> Wt[(n*4+q)*32 + c] (float4) ----
__global__ __launch_bounds__(256)
void wtrans(const float4* __restrict__ W4, float4* __restrict__ Wt)
{
    int idx = blockIdx.x * 256 + threadIdx.x;     // 288*32*4 = 36864 float4
    if (idx < 36864) {
        int n = idx >> 7;
        int r = idx & 127;
        int c = r >> 2, q = r & 3;
        Wt[((n * 4 + q) << 5) + c] = W4[idx];
    }
}

// ---------------- M-pass kernel ----------------
// grid (576, NCH), block 256 (4 waves). Each half-wave owns one n per step;
// lane&31 = output capsule c; thread holds all 16 il as 8 f32x2 pairs.
template<int NCH, bool FIRST>
__global__ __launch_bounds__(256, 4)
void em_pass(const float* __restrict__ x,
             const float* __restrict__ a,
             const float4* __restrict__ Wt,
             const float* __restrict__ bu,
             const float* __restrict__ ba,
             const float* __restrict__ part_r,
             float* __restrict__ part_w)
{
    constexpr int NCAP  = 288 / NCH;
    constexpr int NSTEP = NCAP / 8;
    constexpr int SZ_S  = 576 * NCH * 32 * 16;

    __shared__ __align__(16) float4 pose_s[NCAP * 4];
    __shared__ float ain_s[FIRST ? NCAP : 1];
    __shared__ float SA[2][32][17];                 // S1 (+R in pad slot 16)
    __shared__ float SB[2][32][17];                 // S2
    __shared__ f32x2 php_s[FIRST ? 1 : 32][9];      // {-p} pairs
    __shared__ f32x2 mh_s[FIRST ? 1 : 32][9];       // {2*p*mu} pairs
    __shared__ float A_s[32];                       // folded A (incl. -K)
    __shared__ float AU_s[32];                      // unfolded A (for max bound)

    const int tid  = threadIdx.x;
    const int wv   = tid >> 6;
    const int lane = tid & 63;
    const int half = (lane >> 5) & 1;
    const int c    = lane & 31;

    const int pos = blockIdx.x;
    const int ch  = blockIdx.y;
    const int b   = pos / 36;
    const int rem = pos % 36;
    const int oy  = rem / 6, ox = rem % 6;
    const int iy0 = oy * 2, ix0 = ox * 2;

    // ---- stage pose chunk into LDS ----
    {
        const float4* x4 = (const float4*)x;
        for (int idx = tid; idx < NCAP * 4; idx += 256) {
            int n_l = idx >> 2, j = idx & 3;
            int n_g = ch * NCAP + n_l;
            int seg = n_g >> 5, bi = n_g & 31;
            int kh = seg / 3, kw = seg % 3;
            pose_s[idx] = x4[((b * 14 + iy0 + kh) * 14 + (ix0 + kw)) * 128 + bi * 4 + j];
        }
        if constexpr (FIRST) {
            for (int idx = tid; idx < NCAP; idx += 256) {
                int n_g = ch * NCAP + idx;
                int seg = n_g >> 5, bi = n_g & 31;
                int kh = seg / 3, kw = seg % 3;
                ain_s[idx] = a[((b * 14 + iy0 + kh) * 14 + (ix0 + kw)) * 32 + bi];
            }
        }
    }

    if constexpr (!FIRST) {
        // ---- fused finalize of previous pass's partials -> {-p, 2pmu, A} ----
        const int cf = tid >> 3, k2 = tid & 7;
        float R = 0.f;
        #pragma unroll
        for (int q = 0; q < NCH; ++q)
            R += part_r[2 * (size_t)SZ_S + (pos * NCH + q) * 32 + cf];
        float rinv = __fdividef(1.f, R + 1e-8f);
        float tpart = 0.f, Ks = 0.f;
        #pragma unroll
        for (int t2 = 0; t2 < 2; ++t2) {
            int k = k2 + t2 * 8;
            int base = ((pos * NCH) * 32 + cf) * 16 + k;
            float s1 = 0.f, s2 = 0.f;
            #pragma unroll
            for (int q = 0; q < NCH; ++q) {
                s1 += part_r[base + q * 512];
                s2 += part_r[SZ_S + base + q * 512];
            }
            float mu  = s1 * rinv;
            float sig = fmaf(-mu, mu, s2 * rinv);
            sig = fmaxf(sig, 1e-30f);
            float p = __fdividef(0.5f, sig);
            ((float*)&php_s[cf][0])[k] = -p;
            ((float*)&mh_s[cf][0])[k]  = 2.f * p * mu;
            tpart += __logf(sig);
            Ks = fmaf(p * mu, mu, Ks);
        }
        #pragma unroll
        for (int mk = 4; mk >= 1; mk >>= 1) {
            tpart += __shfl_xor(tpart, mk);
            Ks    += __shfl_xor(Ks, mk);
        }
        float cost = R * fmaf(0.5f, tpart, 16.f * bu[cf]);
        float aout = __fdividef(1.f, 1.f + __expf(-(0.001f * (ba[cf] - cost))));
        if (k2 == 0) {
            float Afold = __logf(aout) - 0.5f * tpart - 8.0f * LN2PI - Ks;
            A_s[cf]  = Afold;
            AU_s[cf] = Afold + Ks;      // unfolded bound source
        }
    }
    __syncthreads();

    f32x2 ph[8], mh[8];
    float Ac = 0.f;
    if constexpr (!FIRST) {
        #pragma unroll
        for (int j = 0; j < 8; ++j) { ph[j] = php_s[c][j]; mh[j] = mh_s[c][j]; }
        float AU = AU_s[c];
        float m = AU;
        #pragma unroll
        for (int mk = 16; mk >= 1; mk >>= 1)
            m = fmaxf(m, __shfl_xor(m, mk));
        Ac = A_s[c] - m;                // lnap - m <= AU - m <= 0 -> exp <= 1
    }

    f32x2 s1[8], s2[8];
    #pragma unroll
    for (int j = 0; j < 8; ++j) { s1[j] = splat2(0.f); s2[j] = splat2(0.f); }
    float Racc = 0.f;

    const int n_l0 = wv * (NCAP / 4) + half;
    const float4* wp = Wt + ((size_t)(ch * NCAP + n_l0) * 4) * 32 + c;
    const float4* pp = pose_s + n_l0 * 4;
    const float* an  = FIRST ? (ain_s + n_l0) : nullptr;

    #pragma unroll
    for (int s = 0; s < NSTEP; ++s) {
        // W rows (coalesced: lanes read consecutive float4s) + pose rows (broadcast)
        float4 wr0 = wp[0], wr1 = wp[32], wr2 = wp[64], wr3 = wp[96];
        float4 pr0 = pp[0], pr1 = pp[1], pr2 = pp[2], pr3 = pp[3];

        f32x2 w2[8];
        w2[0].x = wr0.x; w2[0].y = wr0.y;  w2[1].x = wr0.z; w2[1].y = wr0.w;
        w2[2].x = wr1.x; w2[2].y = wr1.y;  w2[3].x = wr1.z; w2[3].y = wr1.w;
        w2[4].x = wr2.x; w2[4].y = wr2.y;  w2[5].x = wr2.z; w2[5].y = wr2.w;
        w2[6].x = wr3.x; w2[6].y = wr3.y;  w2[7].x = wr3.z; w2[7].y = wr3.w;

        // v2[i*2+lp] = {v[i][2lp], v[i][2lp+1]} = sum_j pose[i][j]*W[j][lp-pair]
        f32x2 v2[8];
        #pragma unroll
        for (int i = 0; i < 4; ++i) {
            float4 pr = (i == 0) ? pr0 : (i == 1) ? pr1 : (i == 2) ? pr2 : pr3;
            #pragma unroll
            for (int lp = 0; lp < 2; ++lp) {
                f32x2 t = splat2(pr.x) * w2[0 + lp];
                t = FMA2(splat2(pr.y), w2[2 + lp], t);
                t = FMA2(splat2(pr.z), w2[4 + lp], t);
                t = FMA2(splat2(pr.w), w2[6 + lp], t);
                v2[i * 2 + lp] = t;
            }
        }

        float r;
        if constexpr (FIRST) {
            r = an[2 * s] * 0.03125f;       // a_in / C
        } else {
            // lnap - M = Ac + sum_il [(-p)v + 2pmu]*v   (<= 0)
            f32x2 acc2 = splat2(0.f);
            acc2.x = Ac;
            #pragma unroll
            for (int j = 0; j < 8; ++j) {
                f32x2 t = FMA2(ph[j], v2[j], mh[j]);
                acc2 = FMA2(t, v2[j], acc2);
            }
            float accf = acc2.x + acc2.y;
            float e = __expf(accf);
            float ssum = sum32(e);
            r = __fdividef(e, ssum + 1e-30f);
        }

        Racc += r;
        f32x2 rr = splat2(r);
        #pragma unroll
        for (int j = 0; j < 8; ++j) {
            f32x2 rv = rr * v2[j];
            s1[j] = s1[j] + rv;
            s2[j] = FMA2(rv, v2[j], s2[j]);
        }

        wp += 256;      // 2 n * 4 q * 32 c
        pp += 8;        // 2 n * 4 rows
    }

    // combine half-wave partials (same c, disjoint n)
    #pragma unroll
    for (int j = 0; j < 8; ++j) {
        s1[j].x += __shfl_xor(s1[j].x, 32);
        s1[j].y += __shfl_xor(s1[j].y, 32);
        s2[j].x += __shfl_xor(s2[j].x, 32);
        s2[j].y += __shfl_xor(s2[j].y, 32);
    }
    Racc += __shfl_xor(Racc, 32);

    // two-phase half-split reduce: half0 -> SA (S1 + R in pad), half1 -> SB (S2)
    if (wv >= 2) {
        const int row = wv - 2;
        if (half == 0) {
            #pragma unroll
            for (int j = 0; j < 8; ++j) {
                SA[row][c][2 * j]     = s1[j].x;
                SA[row][c][2 * j + 1] = s1[j].y;
            }
            SA[row][c][16] = Racc;
        } else {
            #pragma unroll
            for (int j = 0; j < 8; ++j) {
                SB[row][c][2 * j]     = s2[j].x;
                SB[row][c][2 * j + 1] = s2[j].y;
            }
        }
    }
    __syncthreads();
    if (wv < 2) {
        if (half == 0) {
            #pragma unroll
            for (int j = 0; j < 8; ++j) {
                SA[wv][c][2 * j]     += s1[j].x;
                SA[wv][c][2 * j + 1] += s1[j].y;
            }
            SA[wv][c][16] += Racc;
        } else {
            #pragma unroll
            for (int j = 0; j < 8; ++j) {
                SB[wv][c][2 * j]     += s2[j].x;
                SB[wv][c][2 * j + 1] += s2[j].y;
            }
        }
    }
    __syncthreads();

    // write chunk partial to global
    for (int idx = tid; idx < 512; idx += 256) {
        int c2 = idx >> 4, k = idx & 15;
        size_t base = ((size_t)(pos * NCH + ch) * 32 + c2) * 16 + k;
        part_w[base]                  = SA[0][c2][k] + SA[1][c2][k];
        part_w[(size_t)SZ_S + base]   = SB[0][c2][k] + SB[1][c2][k];
    }
    if (tid < 32)
        part_w[2 * (size_t)SZ_S + (pos * NCH + ch) * 32 + tid] =
            SA[0][tid][16] + SA[1][tid][16];
}

// ---------------- final output kernel ----------------
__global__ __launch_bounds__(256)
void em_out(const float* __restrict__ part_r,
            const float* __restrict__ bu,
            const float* __restrict__ ba,
            float* __restrict__ out, int nch)
{
    const int pos = blockIdx.x;
    const int tid = threadIdx.x;
    const int cf = tid >> 3, k2 = tid & 7;
    const size_t SZ_S = (size_t)576 * nch * 512;

    float R = 0.f;
    for (int q = 0; q < nch; ++q)
        R += part_r[2 * SZ_S + (pos * nch + q) * 32 + cf];
    float rinv = __fdividef(1.f, R + 1e-8f);
    float muv[2];
    float tpart = 0.f;
    #pragma unroll
    for (int t2 = 0; t2 < 2; ++t2) {
        int k = k2 + t2 * 8;
        int base = ((pos * nch) * 32 + cf) * 16 + k;
        float s1 = 0.f, s2 = 0.f;
        for (int q = 0; q < nch; ++q) {
            s1 += part_r[base + q * 512];
            s2 += part_r[SZ_S + base + q * 512];
        }
        float mu  = s1 * rinv;
        float sig = fmaf(-mu, mu, s2 * rinv);
        sig = fmaxf(sig, 1e-30f);
        muv[t2] = mu;
        tpart  += __logf(sig);
    }
    #pragma unroll
    for (int mk = 4; mk >= 1; mk >>= 1)
        tpart += __shfl_xor(tpart, mk);
    float cost = R * fmaf(0.5f, tpart, 16.f * bu[cf]);
    float aout = __fdividef(1.f, 1.f + __expf(-(0.001f * (ba[cf] - cost))));

    out[(size_t)pos * 512 + cf * 16 + k2]     = muv[0];
    out[(size_t)pos * 512 + cf * 16 + k2 + 8] = muv[1];
    if (k2 == 0)
        out[294912 + pos * 32 + cf] = aout;
}

// ---------------- legacy single-kernel fallback (R1, known-good 107us) ------
#define NB 288
#define LNSTEP 36
__global__ __launch_bounds__(256, 2)
void convcaps_em_legacy(const float* __restrict__ x, const float* __restrict__ a,
                        const float* __restrict__ W, const float* __restrict__ bu,
                        const float* __restrict__ ba, float* __restrict__ out)
{
    __shared__ __align__(16) float pose_s[NB * 16];
    __shared__ __align__(16) float ain_s[NB];
    __shared__ float S1w[4][32][17];
    __shared__ float S2w[4][32][17];
    __shared__ float Rw[4][32];
    __shared__ float mu_s[32][17];
    __shared__ float p_s[32][17];
    __shared__ float A_s[32];

    const int tid = threadIdx.x, wv = tid >> 6, lane = tid & 63;
    const int half = (lane >> 5) & 1, c = lane & 31;
    const int bid = blockIdx.x, b = bid / 36, rem = bid % 36;
    const int oy = rem / 6, ox = rem % 6, iy0 = oy * 2, ix0 = ox * 2;
    {
        const float4* x4 = (const float4*)x;
        float4* d4 = (float4*)pose_s;
        for (int idx = tid; idx < 1152; idx += 256) {
            int seg = idx >> 7, u = idx & 127, kh = seg / 3, kw = seg % 3;
            d4[idx] = x4[((b * 14 + iy0 + kh) * 14 + (ix0 + kw)) * 128 + u];
        }
        const float4* a4 = (const float4*)a;
        float4* e4 = (float4*)ain_s;
        if (tid < 72) {
            int seg = tid >> 3, u = tid & 7, kh = seg / 3, kw = seg % 3;
            e4[tid] = a4[((b * 14 + iy0 + kh) * 14 + (ix0 + kw)) * 8 + u];
        }
    }
    __syncthreads();
    const float4* W4 = (const float4*)W;
    float muh[16], ph[16], Ac = 0.0f;
    #pragma unroll
    for (int i = 0; i < 16; ++i) { muh[i] = 0.0f; ph[i] = 0.0f; }
    for (int iter = 0; iter < 3; ++iter) {
        if (iter > 0) {
            #pragma unroll
            for (int il = 0; il < 16; ++il) { muh[il] = mu_s[c][il]; ph[il] = p_s[c][il]; }
            Ac = A_s[c];
        }
        float S1[16], S2[16], Racc = 0.0f;
        #pragma unroll
        for (int i = 0; i < 16; ++i) { S1[i] = 0.0f; S2[i] = 0.0f; }
        for (int s = 0; s < LNSTEP; ++s) {
            const int n = wv * 72 + 2 * s + half;
            float wreg[16], preg[16];
            const float4* wp = W4 + (size_t)(n * 32 + c) * 4;
            float4 w0 = wp[0], w1 = wp[1], w2 = wp[2], w3 = wp[3];
            wreg[0]=w0.x; wreg[1]=w0.y; wreg[2]=w0.z; wreg[3]=w0.w;
            wreg[4]=w1.x; wreg[5]=w1.y; wreg[6]=w1.z; wreg[7]=w1.w;
            wreg[8]=w2.x; wreg[9]=w2.y; wreg[10]=w2.z; wreg[11]=w2.w;
            wreg[12]=w3.x; wreg[13]=w3.y; wreg[14]=w3.z; wreg[15]=w3.w;
            const float4* pp = (const float4*)&pose_s[n * 16];
            float4 p0 = pp[0], p1 = pp[1], p2 = pp[2], p3 = pp[3];
            preg[0]=p0.x; preg[1]=p0.y; preg[2]=p0.z; preg[3]=p0.w;
            preg[4]=p1.x; preg[5]=p1.y; preg[6]=p1.z; preg[7]=p1.w;
            preg[8]=p2.x; preg[9]=p2.y; preg[10]=p2.z; preg[11]=p2.w;
            preg[12]=p3.x; preg[13]=p3.y; preg[14]=p3.z; preg[15]=p3.w;
            float v[16];
            #pragma unroll
            for (int i = 0; i < 4; ++i)
                #pragma unroll
                for (int l = 0; l < 4; ++l) {
                    float acc = preg[i*4+0] * wreg[l];
                    acc = fmaf(preg[i*4+1], wreg[4+l], acc);
                    acc = fmaf(preg[i*4+2], wreg[8+l], acc);
                    acc = fmaf(preg[i*4+3], wreg[12+l], acc);
                    v[i*4+l] = acc;
                }
            float r;
            if (iter == 0) r = ain_s[n] * 0.03125f;
            else {
                float acc = 0.0f;
                #pragma unroll
                for (int il = 0; il < 16; ++il) { float d = v[il]-muh[il]; acc = fmaf(-ph[il], d*d, acc); }
                float lnap = Ac + acc, m = lnap;
                #pragma unroll
                for (int mk = 16; mk >= 1; mk >>= 1) m = fmaxf(m, __shfl_xor(m, mk));
                float e = __expf(lnap - m), ssum = e;
                #pragma unroll
                for (int mk = 16; mk >= 1; mk >>= 1) ssum += __shfl_xor(ssum, mk);
                r = __fdividef(e, ssum);
            }
            Racc += r;
            #pragma unroll
            for (int il = 0; il < 16; ++il) { float rv = r * v[il]; S1[il] += rv; S2[il] = fmaf(rv, v[il], S2[il]); }
        }
        #pragma unroll
        for (int il = 0; il < 16; ++il) { S1[il] += __shfl_xor(S1[il], 32); S2[il] += __shfl_xor(S2[il], 32); }
        Racc += __shfl_xor(Racc, 32);
        if (half == 0) {
            #pragma unroll
            for (int il = 0; il < 16; ++il) { S1w[wv][c][il] = S1[il]; S2w[wv][c][il] = S2[il]; }
            Rw[wv][c] = Racc;
        }
        __syncthreads();
        {
            const int c2 = tid >> 3, k = tid & 7;
            float R = Rw[0][c2] + Rw[1][c2] + Rw[2][c2] + Rw[3][c2];
            float rinv = __fdividef(1.0f, R + 1e-8f);
            float muv[2], pv[2], tpart = 0.0f;
            #pragma unroll
            for (int t2 = 0; t2 < 2; ++t2) {
                int il = k + t2 * 8;
                float s1 = S1w[0][c2][il]+S1w[1][c2][il]+S1w[2][c2][il]+S1w[3][c2][il];
                float s2 = S2w[0][c2][il]+S2w[1][c2][il]+S2w[2][c2][il]+S2w[3][c2][il];
                float mu = s1 * rinv;
                float sig = fmaf(-mu, mu, s2 * rinv);
                sig = fmaxf(sig, 1e-30f);
                muv[t2] = mu; pv[t2] = __fdividef(0.5f, sig); tpart += __logf(sig);
            }
            #pragma unroll
            for (int mk = 4; mk >= 1; mk >>= 1) tpart += __shfl_xor(tpart, mk);
            float cost = R * fmaf(0.5f, tpart, 16.0f * bu[c2]);
            float aout = __fdividef(1.0f, 1.0f + __expf(-(0.001f * (ba[c2] - cost))));
            if (iter < 2) {
                #pragma unroll
                for (int t2 = 0; t2 < 2; ++t2) { int il = k + t2*8; mu_s[c2][il] = muv[t2]; p_s[c2][il] = pv[t2]; }
                if (k == 0) A_s[c2] = __logf(aout) - 0.5f * tpart - 8.0f * LN2PI;
            } else {
                #pragma unroll
                for (int t2 = 0; t2 < 2; ++t2) { int il = k + t2*8; out[(size_t)bid*512 + c2*16 + il] = muv[t2]; }
                if (k == 0) out[294912 + bid * 32 + c2] = aout;
            }
        }
        __syncthreads();
    }
}

// ---------------- host ----------------
template<int NCH>
static void run_split(const float* x, const float* a, const float* w,
                      const float* bu, const float* ba, float* out,
                      float* wsf, hipStream_t stream)
{
    const size_t bufN = (size_t)576 * NCH * 32 * 33;
    float* Wt   = wsf;                       // 147456 floats
    float* buf0 = wsf + 147456;
    float* buf1 = buf0 + bufN;
    hipLaunchKernelGGL(wtrans, dim3(144), dim3(256), 0, stream,
                       (const float4*)w, (float4*)Wt);
    hipLaunchKernelGGL((em_pass<NCH, true>),  dim3(576, NCH), dim3(256), 0, stream,
                       x, a, (const float4*)Wt, bu, ba, (const float*)nullptr, buf0);
    hipLaunchKernelGGL((em_pass<NCH, false>), dim3(576, NCH), dim3(256), 0, stream,
                       x, a, (const float4*)Wt, bu, ba, buf0, buf1);
    hipLaunchKernelGGL((em_pass<NCH, false>), dim3(576, NCH), dim3(256), 0, stream,
                       x, a, (const float4*)Wt, bu, ba, buf1, buf0);
    hipLaunchKernelGGL(em_out, dim3(576), dim3(256), 0, stream, buf0, bu, ba, out, NCH);
}

extern "C" void kernel_launch(void* const* d_in, const int* in_sizes, int n_in,
                              void* d_out, int out_size, void* d_ws, size_t ws_size,
                              hipStream_t stream) {
    (void)in_sizes; (void)n_in; (void)out_size;
    const float* x  = (const float*)d_in[0];
    const float* a  = (const float*)d_in[1];
    const float* w  = (const float*)d_in[2];
    const float* bu = (const float*)d_in[3];
    const float* ba = (const float*)d_in[4];
    float* out = (float*)d_out;
    float* wsf = (float*)d_ws;

    auto need = [](int nch) -> size_t {
        return ((size_t)147456 + 2 * (size_t)576 * nch * 32 * 33) * 4;
    };

    if (ws_size >= need(6))      run_split<6>(x, a, w, bu, ba, out, wsf, stream);
    else if (ws_size >= need(4)) run_split<4>(x, a, w, bu, ba, out, wsf, stream);
    else if (ws_size >= need(2)) run_split<2>(x, a, w, bu, ba, out, wsf, stream);
    else
        hipLaunchKernelGGL(convcaps_em_legacy, dim3(576), dim3(256), 0, stream,
                           x, a, w, bu, ba, out);
}

// Round 9
// 85.564 us; speedup vs baseline: 6.6318x; 1.3474x over previous
//
#include <hip/hip_runtime.h>

// ConvCaps EM routing, MI355X — fused single kernel + one-time W transpose.
// Geometry: b=16 -> 576 positions; N=288 input caps; C=32; ITERS=3.
//
// R1 fused (fat loop): 107us. R4-R8 split: E-pass down to 44us but total 115us
// (3x staging + partials round-trip + extra launches eat the gain).
// R2/R5: launch_bounds min-waves below natural VGPR -> total spill. NEVER.
// R7: cooperative grid.sync hung. NEVER.
// R9: R1's fused structure (pose staged once, 3 iters + finalize in-block,
// zero partial traffic) with R8's measured inner-loop wins: coalesced Wt
// (stride-64B gather -> contiguous dwordx4), packed f32x2 v_pk_fma_f32,
// folded E-step (t=fma(-p,v,2pmu); acc=fma(t,v,acc); sum p*mu^2 in A),
// DPP softmax sum, hoisted per-iter max bound, half-split LDS reduce.

#define LN2PI 1.8378770664093453f

typedef __attribute__((ext_vector_type(2))) float f32x2;
#define FMA2(a, b, c) __builtin_elementwise_fma((a), (b), (c))
__device__ __forceinline__ f32x2 splat2(float x) { f32x2 r; r.x = x; r.y = x; return r; }

// DPP butterfly add over 32-lane group (never crosses the half-wave boundary).
#define DPP_ADD(x, ctrl) \
    ((x) + __int_as_float(__builtin_amdgcn_update_dpp( \
        0, __float_as_int(x), (ctrl), 0xF, 0xF, true)))

__device__ __forceinline__ float sum32(float e) {
    float s = e;
    s = DPP_ADD(s, 0xB1);   // quad_perm(1,0,3,2): xor1
    s = DPP_ADD(s, 0x4E);   // quad_perm(2,3,0,1): xor2
    s = DPP_ADD(s, 0x141);  // row_half_mirror: xor4
    s = DPP_ADD(s, 0x140);  // row_mirror:      xor8
    s += __shfl_xor(s, 16);
    return s;
}

// ---------------- W transpose: W[n][c][q] -> Wt[(n*4+q)*32 + c] (float4) ----
__global__ __launch_bounds__(256)
void wtrans(const float4* __restrict__ W4, float4* __restrict__ Wt)
{
    int idx = blockIdx.x * 256 + threadIdx.x;     // 288*32*4 = 36864 float4
    if (idx < 36864) {
        int n = idx >> 7;
        int r = idx & 127;
        int c = r >> 2, q = r & 3;
        Wt[((n * 4 + q) << 5) + c] = W4[idx];
    }
}

// ---------------- fused EM kernel ----------------
// 576 blocks (1/position), 256 thr (4 waves). Each half-wave owns one n per
// step (8 n/step, NSTEP=36); lane&31 = output capsule c; thread holds 16 il
// as 8 f32x2 pairs.
__global__ __launch_bounds__(256)
void em_fused(const float* __restrict__ x,
              const float* __restrict__ a,
              const float4* __restrict__ Wt,
              const float* __restrict__ bu,
              const float* __restrict__ ba,
              float* __restrict__ out)
{
    __shared__ __align__(16) float4 pose_s[288 * 4];   // 18432 B
    __shared__ float ain_s[288];                       //  1152 B
    __shared__ float SA[2][32][17];                    //  4352 B (S1 + R in pad)
    __shared__ float SB[2][32][17];                    //  4352 B (S2)
    __shared__ f32x2 php_s[32][9];                     //  2304 B ({-p})
    __shared__ f32x2 mh_s[32][9];                      //  2304 B ({2 p mu})
    __shared__ float A_s[32];                          //   128 B (folded)
    __shared__ float AU_s[32];                         //   128 B (bound)
    // ~33 KB

    const int tid  = threadIdx.x;
    const int wv   = tid >> 6;
    const int lane = tid & 63;
    const int half = (lane >> 5) & 1;
    const int c    = lane & 31;

    const int pos = blockIdx.x;          // b*36 + oy*6 + ox
    const int b   = pos / 36;
    const int rem = pos % 36;
    const int oy  = rem / 6, ox = rem % 6;
    const int iy0 = oy * 2, ix0 = ox * 2;

    // ---- stage pose patch (1152 float4) + a patch once ----
    {
        const float4* x4 = (const float4*)x;
        for (int idx = tid; idx < 1152; idx += 256) {
            int seg = idx >> 7, u = idx & 127;
            int kh = seg / 3, kw = seg % 3;
            pose_s[idx] = x4[((b * 14 + iy0 + kh) * 14 + (ix0 + kw)) * 128 + u];
        }
        const float4* a4 = (const float4*)a;
        float4* e4 = (float4*)ain_s;
        if (tid < 72) {
            int seg = tid >> 3, u = tid & 7;
            int kh = seg / 3, kw = seg % 3;
            e4[tid] = a4[((b * 14 + iy0 + kh) * 14 + (ix0 + kw)) * 8 + u];
        }
    }
    __syncthreads();

    const int n0 = wv * 72 + half;       // first n for this half-wave

    for (int it = 0; it < 3; ++it) {
        f32x2 ph[8], mh[8];
        float Ac = 0.f;
        if (it > 0) {
            #pragma unroll
            for (int j = 0; j < 8; ++j) { ph[j] = php_s[c][j]; mh[j] = mh_s[c][j]; }
            float AU = AU_s[c];
            float m = AU;
            #pragma unroll
            for (int mk = 16; mk >= 1; mk >>= 1)
                m = fmaxf(m, __shfl_xor(m, mk));
            Ac = A_s[c] - m;             // lnap - m <= 0 -> exp <= 1
        }

        f32x2 s1[8], s2[8];
        #pragma unroll
        for (int j = 0; j < 8; ++j) { s1[j] = splat2(0.f); s2[j] = splat2(0.f); }
        float Racc = 0.f;

        const float4* wp = Wt + (size_t)n0 * 128 + c;
        const float4* pp = pose_s + n0 * 4;
        const float* an  = ain_s + n0;

        #define STEP_BODY(USE_SM)                                              \
        {                                                                      \
            float4 wr0 = wp[0], wr1 = wp[32], wr2 = wp[64], wr3 = wp[96];      \
            float4 pr0 = pp[0], pr1 = pp[1], pr2 = pp[2], pr3 = pp[3];         \
            f32x2 w2[8];                                                       \
            w2[0].x = wr0.x; w2[0].y = wr0.y;  w2[1].x = wr0.z; w2[1].y = wr0.w;\
            w2[2].x = wr1.x; w2[2].y = wr1.y;  w2[3].x = wr1.z; w2[3].y = wr1.w;\
            w2[4].x = wr2.x; w2[4].y = wr2.y;  w2[5].x = wr2.z; w2[5].y = wr2.w;\
            w2[6].x = wr3.x; w2[6].y = wr3.y;  w2[7].x = wr3.z; w2[7].y = wr3.w;\
            f32x2 v2[8];                                                       \
            _Pragma("unroll")                                                  \
            for (int i = 0; i < 4; ++i) {                                      \
                float4 pr = (i == 0) ? pr0 : (i == 1) ? pr1 : (i == 2) ? pr2 : pr3; \
                _Pragma("unroll")                                              \
                for (int lp = 0; lp < 2; ++lp) {                               \
                    f32x2 t = splat2(pr.x) * w2[0 + lp];                       \
                    t = FMA2(splat2(pr.y), w2[2 + lp], t);                     \
                    t = FMA2(splat2(pr.z), w2[4 + lp], t);                     \
                    t = FMA2(splat2(pr.w), w2[6 + lp], t);                     \
                    v2[i * 2 + lp] = t;                                        \
                }                                                              \
            }                                                                  \
            float r;                                                           \
            if (USE_SM) {                                                      \
                f32x2 acc2 = splat2(0.f);                                      \
                acc2.x = Ac;                                                   \
                _Pragma("unroll")                                              \
                for (int j = 0; j < 8; ++j) {                                  \
                    f32x2 t = FMA2(ph[j], v2[j], mh[j]);                       \
                    acc2 = FMA2(t, v2[j], acc2);                               \
                }                                                              \
                float e = __expf(acc2.x + acc2.y);                             \
                float ssum = sum32(e);                                         \
                r = __fdividef(e, ssum + 1e-30f);                              \
            } else {                                                           \
                r = an[2 * s] * 0.03125f;                                      \
            }                                                                  \
            Racc += r;                                                         \
            f32x2 rr = splat2(r);                                              \
            _Pragma("unroll")                                                  \
            for (int j = 0; j < 8; ++j) {                                      \
                f32x2 rv = rr * v2[j];                                         \
                s1[j] = s1[j] + rv;                                            \
                s2[j] = FMA2(rv, v2[j], s2[j]);                                \
            }                                                                  \
            wp += 256;                                                         \
            pp += 8;                                                           \
        }

        if (it == 0) {
            for (int s = 0; s < 36; ++s) STEP_BODY(false)
        } else {
            for (int s = 0; s < 36; ++s) STEP_BODY(true)
        }
        #undef STEP_BODY

        // combine half-wave partials (same c, disjoint n)
        #pragma unroll
        for (int j = 0; j < 8; ++j) {
            s1[j].x += __shfl_xor(s1[j].x, 32);
            s1[j].y += __shfl_xor(s1[j].y, 32);
            s2[j].x += __shfl_xor(s2[j].x, 32);
            s2[j].y += __shfl_xor(s2[j].y, 32);
        }
        Racc += __shfl_xor(Racc, 32);

        // half-split two-phase reduce: half0 -> SA (S1 + R), half1 -> SB (S2)
        if (wv >= 2) {
            const int row = wv - 2;
            if (half == 0) {
                #pragma unroll
                for (int j = 0; j < 8; ++j) {
                    SA[row][c][2 * j]     = s1[j].x;
                    SA[row][c][2 * j + 1] = s1[j].y;
                }
                SA[row][c][16] = Racc;
            } else {
                #pragma unroll
                for (int j = 0; j < 8; ++j) {
                    SB[row][c][2 * j]     = s2[j].x;
                    SB[row][c][2 * j + 1] = s2[j].y;
                }
            }
        }
        __syncthreads();
        if (wv < 2) {
            if (half == 0) {
                #pragma unroll
                for (int j = 0; j < 8; ++j) {
                    SA[wv][c][2 * j]     += s1[j].x;
                    SA[wv][c][2 * j + 1] += s1[j].y;
                }
                SA[wv][c][16] += Racc;
            } else {
                #pragma unroll
                for (int j = 0; j < 8; ++j) {
                    SB[wv][c][2 * j]     += s2[j].x;
                    SB[wv][c][2 * j + 1] += s2[j].y;
                }
            }
        }
        __syncthreads();

        // ---- in-block finalize: thread = cf*8 + k2 handles il = k2, k2+8 ----
        {
            const int cf = tid >> 3, k2 = tid & 7;
            float R = SA[0][cf][16] + SA[1][cf][16];
            float rinv = __fdividef(1.f, R + 1e-8f);
            float muv[2];
            float tpart = 0.f, Ks = 0.f;
            #pragma unroll
            for (int t2 = 0; t2 < 2; ++t2) {
                int k = k2 + t2 * 8;
                float sv1 = SA[0][cf][k] + SA[1][cf][k];
                float sv2 = SB[0][cf][k] + SB[1][cf][k];
                float mu  = sv1 * rinv;
                float sig = fmaf(-mu, mu, sv2 * rinv);
                sig = fmaxf(sig, 1e-30f);
                float p = __fdividef(0.5f, sig);
                muv[t2] = mu;
                if (it < 2) {
                    ((float*)&php_s[cf][0])[k] = -p;
                    ((float*)&mh_s[cf][0])[k]  = 2.f * p * mu;
                }
                tpart += __logf(sig);
                Ks = fmaf(p * mu, mu, Ks);
            }
            #pragma unroll
            for (int mk = 4; mk >= 1; mk >>= 1) {
                tpart += __shfl_xor(tpart, mk);
                Ks    += __shfl_xor(Ks, mk);
            }
            float cost = R * fmaf(0.5f, tpart, 16.f * bu[cf]);
            float aout = __fdividef(1.f, 1.f + __expf(-(0.001f * (ba[cf] - cost))));

            if (it < 2) {
                if (k2 == 0) {
                    float Afold = __logf(aout) - 0.5f * tpart - 8.0f * LN2PI - Ks;
                    A_s[cf]  = Afold;
                    AU_s[cf] = Afold + Ks;
                }
            } else {
                out[(size_t)pos * 512 + cf * 16 + k2]     = muv[0];
                out[(size_t)pos * 512 + cf * 16 + k2 + 8] = muv[1];
                if (k2 == 0)
                    out[294912 + pos * 32 + cf] = aout;
            }
        }
        __syncthreads();
    }
}

// ---------------- legacy single-kernel fallback (R1, known-good 107us) ------
#define NB 288
#define LNSTEP 36
__global__ __launch_bounds__(256, 2)
void convcaps_em_legacy(const float* __restrict__ x, const float* __restrict__ a,
                        const float* __restrict__ W, const float* __restrict__ bu,
                        const float* __restrict__ ba, float* __restrict__ out)
{
    __shared__ __align__(16) float pose_s[NB * 16];
    __shared__ __align__(16) float ain_s[NB];
    __shared__ float S1w[4][32][17];
    __shared__ float S2w[4][32][17];
    __shared__ float Rw[4][32];
    __shared__ float mu_s[32][17];
    __shared__ float p_s[32][17];
    __shared__ float A_s[32];

    const int tid = threadIdx.x, wv = tid >> 6, lane = tid & 63;
    const int half = (lane >> 5) & 1, c = lane & 31;
    const int bid = blockIdx.x, b = bid / 36, rem = bid % 36;
    const int oy = rem / 6, ox = rem % 6, iy0 = oy * 2, ix0 = ox * 2;
    {
        const float4* x4 = (const float4*)x;
        float4* d4 = (float4*)pose_s;
        for (int idx = tid; idx < 1152; idx += 256) {
            int seg = idx >> 7, u = idx & 127, kh = seg / 3, kw = seg % 3;
            d4[idx] = x4[((b * 14 + iy0 + kh) * 14 + (ix0 + kw)) * 128 + u];
        }
        const float4* a4 = (const float4*)a;
        float4* e4 = (float4*)ain_s;
        if (tid < 72) {
            int seg = tid >> 3, u = tid & 7, kh = seg / 3, kw = seg % 3;
            e4[tid] = a4[((b * 14 + iy0 + kh) * 14 + (ix0 + kw)) * 8 + u];
        }
    }
    __syncthreads();
    const float4* W4 = (const float4*)W;
    float muh[16], ph[16], Ac = 0.0f;
    #pragma unroll
    for (int i = 0; i < 16; ++i) { muh[i] = 0.0f; ph[i] = 0.0f; }
    for (int iter = 0; iter < 3; ++iter) {
        if (iter > 0) {
            #pragma unroll
            for (int il = 0; il < 16; ++il) { muh[il] = mu_s[c][il]; ph[il] = p_s[c][il]; }
            Ac = A_s[c];
        }
        float S1[16], S2[16], Racc = 0.0f;
        #pragma unroll
        for (int i = 0; i < 16; ++i) { S1[i] = 0.0f; S2[i] = 0.0f; }
        for (int s = 0; s < LNSTEP; ++s) {
            const int n = wv * 72 + 2 * s + half;
            float wreg[16], preg[16];
            const float4* wp = W4 + (size_t)(n * 32 + c) * 4;
            float4 w0 = wp[0], w1 = wp[1], w2 = wp[2], w3 = wp[3];
            wreg[0]=w0.x; wreg[1]=w0.y; wreg[2]=w0.z; wreg[3]=w0.w;
            wreg[4]=w1.x; wreg[5]=w1.y; wreg[6]=w1.z; wreg[7]=w1.w;
            wreg[8]=w2.x; wreg[9]=w2.y; wreg[10]=w2.z; wreg[11]=w2.w;
            wreg[12]=w3.x; wreg[13]=w3.y; wreg[14]=w3.z; wreg[15]=w3.w;
            const float4* pp = (const float4*)&pose_s[n * 16];
            float4 p0 = pp[0], p1 = pp[1], p2 = pp[2], p3 = pp[3];
            preg[0]=p0.x; preg[1]=p0.y; preg[2]=p0.z; preg[3]=p0.w;
            preg[4]=p1.x; preg[5]=p1.y; preg[6]=p1.z; preg[7]=p1.w;
            preg[8]=p2.x; preg[9]=p2.y; preg[10]=p2.z; preg[11]=p2.w;
            preg[12]=p3.x; preg[13]=p3.y; preg[14]=p3.z; preg[15]=p3.w;
            float v[16];
            #pragma unroll
            for (int i = 0; i < 4; ++i)
                #pragma unroll
                for (int l = 0; l < 4; ++l) {
                    float acc = preg[i*4+0] * wreg[l];
                    acc = fmaf(preg[i*4+1], wreg[4+l], acc);
                    acc = fmaf(preg[i*4+2], wreg[8+l], acc);
                    acc = fmaf(preg[i*4+3], wreg[12+l], acc);
                    v[i*4+l] = acc;
                }
            float r;
            if (iter == 0) r = ain_s[n] * 0.03125f;
            else {
                float acc = 0.0f;
                #pragma unroll
                for (int il = 0; il < 16; ++il) { float d = v[il]-muh[il]; acc = fmaf(-ph[il], d*d, acc); }
                float lnap = Ac + acc, m = lnap;
                #pragma unroll
                for (int mk = 16; mk >= 1; mk >>= 1) m = fmaxf(m, __shfl_xor(m, mk));
                float e = __expf(lnap - m), ssum = e;
                #pragma unroll
                for (int mk = 16; mk >= 1; mk >>= 1) ssum += __shfl_xor(ssum, mk);
                r = __fdividef(e, ssum);
            }
            Racc += r;
            #pragma unroll
            for (int il = 0; il < 16; ++il) { float rv = r * v[il]; S1[il] += rv; S2[il] = fmaf(rv, v[il], S2[il]); }
        }
        #pragma unroll
        for (int il = 0; il < 16; ++il) { S1[il] += __shfl_xor(S1[il], 32); S2[il] += __shfl_xor(S2[il], 32); }
        Racc += __shfl_xor(Racc, 32);
        if (half == 0) {
            #pragma unroll
            for (int il = 0; il < 16; ++il) { S1w[wv][c][il] = S1[il]; S2w[wv][c][il] = S2[il]; }
            Rw[wv][c] = Racc;
        }
        __syncthreads();
        {
            const int c2 = tid >> 3, k = tid & 7;
            float R = Rw[0][c2] + Rw[1][c2] + Rw[2][c2] + Rw[3][c2];
            float rinv = __fdividef(1.0f, R + 1e-8f);
            float muv[2], pv[2], tpart = 0.0f;
            #pragma unroll
            for (int t2 = 0; t2 < 2; ++t2) {
                int il = k + t2 * 8;
                float s1 = S1w[0][c2][il]+S1w[1][c2][il]+S1w[2][c2][il]+S1w[3][c2][il];
                float s2 = S2w[0][c2][il]+S2w[1][c2][il]+S2w[2][c2][il]+S2w[3][c2][il];
                float mu = s1 * rinv;
                float sig = fmaf(-mu, mu, s2 * rinv);
                sig = fmaxf(sig, 1e-30f);
                muv[t2] = mu; pv[t2] = __fdividef(0.5f, sig); tpart += __logf(sig);
            }
            #pragma unroll
            for (int mk = 4; mk >= 1; mk >>= 1) tpart += __shfl_xor(tpart, mk);
            float cost = R * fmaf(0.5f, tpart, 16.0f * bu[c2]);
            float aout = __fdividef(1.0f, 1.0f + __expf(-(0.001f * (ba[c2] - cost))));
            if (iter < 2) {
                #pragma unroll
                for (int t2 = 0; t2 < 2; ++t2) { int il = k + t2*8; mu_s[c2][il] = muv[t2]; p_s[c2][il] = pv[t2]; }
                if (k == 0) A_s[c2] = __logf(aout) - 0.5f * tpart - 8.0f * LN2PI;
            } else {
                #pragma unroll
                for (int t2 = 0; t2 < 2; ++t2) { int il = k + t2*8; out[(size_t)bid*512 + c2*16 + il] = muv[t2]; }
                if (k == 0) out[294912 + bid * 32 + c2] = aout;
            }
        }
        __syncthreads();
    }
}

// ---------------- host ----------------
extern "C" void kernel_launch(void* const* d_in, const int* in_sizes, int n_in,
                              void* d_out, int out_size, void* d_ws, size_t ws_size,
                              hipStream_t stream) {
    (void)in_sizes; (void)n_in; (void)out_size;
    const float* x  = (const float*)d_in[0];
    const float* a  = (const float*)d_in[1];
    const float* w  = (const float*)d_in[2];
    const float* bu = (const float*)d_in[3];
    const float* ba = (const float*)d_in[4];
    float* out = (float*)d_out;
    float* wsf = (float*)d_ws;

    if (ws_size >= (size_t)147456 * 4) {
        float* Wt = wsf;                 // 147456 floats = 576 KB
        hipLaunchKernelGGL(wtrans, dim3(144), dim3(256), 0, stream,
                           (const float4*)w, (float4*)Wt);
        hipLaunchKernelGGL(em_fused, dim3(576), dim3(256), 0, stream,
                           x, a, (const float4*)Wt, bu, ba, out);
    } else {
        hipLaunchKernelGGL(convcaps_em_legacy, dim3(576), dim3(256), 0, stream,
                           x, a, w, bu, ba, out);
    }
}